// Round 3
// baseline (212.503 us; speedup 1.0000x reference)
//
#include <hip/hip_runtime.h>

// Problem constants (match reference)
#define BB 64
#define N_WAY 5
#define N_SHOT 5
#define QUERY 15
#define NUM_SLOT 8
#define DD 640
#define IMGS (N_WAY * QUERY)      // 75
#define NS (BB * N_WAY * N_SHOT)  // 1600 support rows
#define NROWS 6400                // total rows
#define ROWSZ (NUM_SLOT * DD)     // 5120 floats per row
#define F4_PER_SLOT 160           // 640/4
#define NELEM (BB * IMGS)         // 4800 loss elements
#define NGROUP (BB * N_WAY)       // 320 support groups

// ---------------- K1: single streaming pass over out_f ----------------
// Produces: rowmean[6400][8]  (per-row per-slot mean over d)
//           proto_all[320][8][640] (shot-mean for every slot)
//           pn2_all[320][8]   (||proto||^2 for every slot)
// Also zeroes the last-block counter for K3.
// Grid: 320 support-group blocks + 4800 query-row blocks, 256 threads each
// (8 slots x 32 lanes, float4 loads).
__global__ __launch_bounds__(256) void k_pass1(const float* __restrict__ out_f,
                                               float* __restrict__ rowmean,
                                               float* __restrict__ proto_all,
                                               float* __restrict__ pn2_all,
                                               int* __restrict__ counter) {
    int b = blockIdx.x;
    int t = threadIdx.x;
    if (b == 0 && t == 0) *counter = 0;
    int slot = t >> 5;            // 0..7
    int l = t & 31;
    if (b < NGROUP) {
        // support group g = j*5+c: 5 shot rows
        const int g = b;
        float4 acc[5];
        #pragma unroll
        for (int k = 0; k < 5; ++k) acc[k] = make_float4(0.f, 0.f, 0.f, 0.f);
        #pragma unroll
        for (int sh = 0; sh < N_SHOT; ++sh) {
            const float4* p = (const float4*)(out_f +
                ((size_t)((g * N_SHOT + sh) * NUM_SLOT + slot)) * DD);
            float s = 0.f;
            #pragma unroll
            for (int k = 0; k < 5; ++k) {
                float4 v = p[l + k * 32];
                acc[k].x += v.x; acc[k].y += v.y; acc[k].z += v.z; acc[k].w += v.w;
                s += (v.x + v.y) + (v.z + v.w);
            }
            #pragma unroll
            for (int off = 16; off; off >>= 1) s += __shfl_down(s, off, 32);
            if (l == 0) rowmean[(g * N_SHOT + sh) * NUM_SLOT + slot] = s * (1.f / DD);
        }
        float4* pp = (float4*)(proto_all + ((size_t)(g * NUM_SLOT + slot)) * DD);
        float ssq = 0.f;
        #pragma unroll
        for (int k = 0; k < 5; ++k) {
            acc[k].x *= 0.2f; acc[k].y *= 0.2f; acc[k].z *= 0.2f; acc[k].w *= 0.2f;
            pp[l + k * 32] = acc[k];
            ssq += acc[k].x * acc[k].x + acc[k].y * acc[k].y
                 + acc[k].z * acc[k].z + acc[k].w * acc[k].w;
        }
        #pragma unroll
        for (int off = 16; off; off >>= 1) ssq += __shfl_down(ssq, off, 32);
        if (l == 0) pn2_all[g * NUM_SLOT + slot] = ssq;
    } else {
        // query row
        int r = NS + (b - NGROUP);
        const float4* p = (const float4*)(out_f + (size_t)r * ROWSZ) + slot * F4_PER_SLOT;
        float s = 0.f;
        #pragma unroll
        for (int k = 0; k < 5; ++k) {
            float4 v = p[l + k * 32];
            s += (v.x + v.y) + (v.z + v.w);
        }
        #pragma unroll
        for (int off = 16; off; off >>= 1) s += __shfl_down(s, off, 32);
        if (l == 0) rowmean[r * NUM_SLOT + slot] = s * (1.f / DD);
    }
}

// ---------------- K2: cover-select + wave-parallel prefix argmax ----------------
// One block (one wave) per batch.
__global__ __launch_bounds__(64) void k_select(const float* __restrict__ rowmean,
                                               int* __restrict__ max_s,
                                               int* __restrict__ k_idx) {
    int j = blockIdx.x;           // 0..63
    int t = threadIdx.x;          // 0..63
    __shared__ float supm[N_WAY * NUM_SLOT];  // [c*8+s]
    __shared__ int msS[N_WAY];
    __shared__ float qb[IMGS * NUM_SLOT];     // 600

    // stage query row-means for this batch
    const float* qbase = rowmean + (size_t)(NS + j * IMGS) * NUM_SLOT;
    for (int i = t; i < IMGS * NUM_SLOT; i += 64) qb[i] = qbase[i];
    // support slot means (mean over shots of per-row means)
    if (t < N_WAY * NUM_SLOT) {
        int c = t >> 3, s = t & 7;
        const float* sb = rowmean + (size_t)j * (N_WAY * N_SHOT * NUM_SLOT)
                          + c * (N_SHOT * NUM_SLOT) + s;
        float a = sb[0] + sb[8] + sb[16] + sb[24] + sb[32];
        supm[t] = a * 0.2f;
    }
    __syncthreads();

    // greedy cover select (serial, tiny; first-occurrence argmax among untaken)
    if (t == 0) {
        unsigned taken = 0u;
        #pragma unroll
        for (int c = 0; c < N_WAY; ++c) {
            float best = -3.0e38f; int bi = 0;
            #pragma unroll
            for (int s = 0; s < NUM_SLOT; ++s) {
                float v = supm[c * NUM_SLOT + s];
                if (!((taken >> s) & 1u) && v > best) { best = v; bi = s; }
            }
            taken |= (1u << bi);
            msS[c] = bi;
            max_s[j * N_WAY + c] = bi;
        }
    }
    __syncthreads();
    int ms0 = msS[0], ms1 = msS[1], ms2 = msS[2], ms3 = msS[3], ms4 = msS[4];

    // per-step local argmax for step s = t (flat index s*5+c, first occurrence)
    float bv; int bi;
    {
        const float* q = &qb[t * NUM_SLOT];
        bv = q[ms0]; bi = t * N_WAY;
        float v;
        v = q[ms1]; if (v > bv) { bv = v; bi = t * N_WAY + 1; }
        v = q[ms2]; if (v > bv) { bv = v; bi = t * N_WAY + 2; }
        v = q[ms3]; if (v > bv) { bv = v; bi = t * N_WAY + 3; }
        v = q[ms4]; if (v > bv) { bv = v; bi = t * N_WAY + 4; }
    }
    // inclusive prefix scan over 64 steps; combine(earlier, later):
    // take later only if strictly greater (preserves first-occurrence)
    #pragma unroll
    for (int off = 1; off < 64; off <<= 1) {
        float ov = __shfl_up(bv, off, 64);
        int   oi = __shfl_up(bi, off, 64);
        if (t >= off && !(bv > ov)) { bv = ov; bi = oi; }
    }
    k_idx[j * IMGS + t] = bi;      // steps 0..63
    // total of first 64 steps
    float tv = __shfl(bv, 63, 64);
    int   ti = __shfl(bi, 63, 64);
    // steps 64..74 on lanes 0..10
    float bv2 = -3.0e38f; int bi2 = 0;
    if (t < IMGS - 64) {
        int s = 64 + t;
        const float* q = &qb[s * NUM_SLOT];
        bv2 = q[ms0]; bi2 = s * N_WAY;
        float v;
        v = q[ms1]; if (v > bv2) { bv2 = v; bi2 = s * N_WAY + 1; }
        v = q[ms2]; if (v > bv2) { bv2 = v; bi2 = s * N_WAY + 2; }
        v = q[ms3]; if (v > bv2) { bv2 = v; bi2 = s * N_WAY + 3; }
        v = q[ms4]; if (v > bv2) { bv2 = v; bi2 = s * N_WAY + 4; }
    }
    #pragma unroll
    for (int off = 1; off < 16; off <<= 1) {
        float ov = __shfl_up(bv2, off, 64);
        int   oi = __shfl_up(bi2, off, 64);
        if (t >= off && t < IMGS - 64 && !(bv2 > ov)) { bv2 = ov; bi2 = oi; }
    }
    if (t < IMGS - 64) {
        if (!(bv2 > tv)) { bv2 = tv; bi2 = ti; }
        k_idx[j * IMGS + 64 + t] = bi2;
    }
}

// ---------------- K3: scores + log-softmax + loss/acc, fused final reduction ----
// score_n = 2 q.p_n - ||p_n||^2  (||q||^2 cancels in log_softmax/argmax)
__global__ __launch_bounds__(64) void k_loss(const float* __restrict__ out_f,
                                             const float* __restrict__ proto_all,
                                             const float* __restrict__ pn2_all,
                                             const int* __restrict__ max_s,
                                             const int* __restrict__ k_idx,
                                             const int* __restrict__ labels_query,
                                             const float* __restrict__ att_loss,
                                             float* __restrict__ part,
                                             int* __restrict__ counter,
                                             float* __restrict__ out) {
    __shared__ int lastflag;
    int bid = blockIdx.x;             // j*75 + m
    int j = bid / IMGS, m = bid % IMGS;
    int t = threadIdx.x;              // 64

    int ms1 = max_s[j * N_WAY + m / QUERY];
    const float4* q1 = (const float4*)(out_f +
        (size_t)(NS + bid) * ROWSZ + ms1 * DD);

    int kk = k_idx[bid];
    int s2 = kk / N_WAY, c2 = kk % N_WAY;
    int ms2 = max_s[j * N_WAY + c2];
    const float4* q2 = (const float4*)(out_f +
        (size_t)(NS + j * IMGS + s2) * ROWSZ + ms2 * DD);

    // per-class proto pointers (selected slot of each class)
    const float4* pr[N_WAY];
    float p2v[N_WAY];
    #pragma unroll
    for (int n = 0; n < N_WAY; ++n) {
        int g = j * N_WAY + n;
        int msn = max_s[g];
        pr[n] = (const float4*)(proto_all + ((size_t)(g * NUM_SLOT + msn)) * DD);
        p2v[n] = pn2_all[g * NUM_SLOT + msn];
    }

    float s1[N_WAY] = {0, 0, 0, 0, 0};
    float s2a[N_WAY] = {0, 0, 0, 0, 0};
    for (int i = t; i < F4_PER_SLOT; i += 64) {
        float4 a = q1[i];
        float4 bq = q2[i];
        #pragma unroll
        for (int n = 0; n < N_WAY; ++n) {
            float4 p = pr[n][i];
            s1[n]  += a.x * p.x + a.y * p.y + a.z * p.z + a.w * p.w;
            s2a[n] += bq.x * p.x + bq.y * p.y + bq.z * p.z + bq.w * p.w;
        }
    }
    #pragma unroll
    for (int n = 0; n < N_WAY; ++n) {
        #pragma unroll
        for (int off = 32; off; off >>= 1) {
            s1[n]  += __shfl_down(s1[n],  off, 64);
            s2a[n] += __shfl_down(s2a[n], off, 64);
        }
    }
    if (t == 0) {
        int label = labels_query[bid];
        // path 1
        {
            float li[N_WAY]; float mx = -3.0e38f;
            #pragma unroll
            for (int n = 0; n < N_WAY; ++n) { li[n] = 2.f * s1[n] - p2v[n]; mx = fmaxf(mx, li[n]); }
            float se = 0.f;
            #pragma unroll
            for (int n = 0; n < N_WAY; ++n) se += expf(li[n] - mx);
            float lse = mx + logf(se);
            int bi = 0; float bvv = li[0];
            #pragma unroll
            for (int n = 1; n < N_WAY; ++n) if (li[n] > bvv) { bvv = li[n]; bi = n; }
            part[0 * NELEM + bid] = -(li[label] - lse);
            part[2 * NELEM + bid] = (bi == label) ? 1.f : 0.f;
        }
        // path 2
        {
            float li[N_WAY]; float mx = -3.0e38f;
            #pragma unroll
            for (int n = 0; n < N_WAY; ++n) { li[n] = 2.f * s2a[n] - p2v[n]; mx = fmaxf(mx, li[n]); }
            float se = 0.f;
            #pragma unroll
            for (int n = 0; n < N_WAY; ++n) se += expf(li[n] - mx);
            float lse = mx + logf(se);
            int bi = 0; float bvv = li[0];
            #pragma unroll
            for (int n = 1; n < N_WAY; ++n) if (li[n] > bvv) { bvv = li[n]; bi = n; }
            part[1 * NELEM + bid] = -(li[label] - lse);
            part[3 * NELEM + bid] = (bi == label) ? 1.f : 0.f;
        }
        __threadfence();
        int prev = atomicAdd(counter, 1);
        lastflag = (prev == NELEM - 1) ? 1 : 0;
    }
    __syncthreads();
    if (lastflag) {
        __threadfence();  // see all other blocks' part writes
        #pragma unroll
        for (int c = 0; c < 4; ++c) {
            float s = 0.f;
            for (int i = t; i < NELEM; i += 64) s += part[c * NELEM + i];
            #pragma unroll
            for (int off = 32; off; off >>= 1) s += __shfl_down(s, off, 64);
            if (t == 0) {
                float v = s / (float)NELEM;
                if (c == 0) v += 0.1f * att_loss[0];
                out[c] = v;
            }
        }
    }
}

extern "C" void kernel_launch(void* const* d_in, const int* in_sizes, int n_in,
                              void* d_out, int out_size, void* d_ws, size_t ws_size,
                              hipStream_t stream) {
    const float* out_f        = (const float*)d_in[0];
    // d_in[1] = labels_support (unused by the reference's train path)
    const int*   labels_query = (const int*)d_in[2];
    const float* att_loss     = (const float*)d_in[3];
    float* out = (float*)d_out;

    // workspace layout
    float* rowmean   = (float*)d_ws;                         // 6400*8
    float* proto_all = rowmean + NROWS * NUM_SLOT;           // 320*8*640
    float* pn2_all   = proto_all + NGROUP * NUM_SLOT * DD;   // 2560
    float* part      = pn2_all + NGROUP * NUM_SLOT;          // 4*4800
    int*   max_s     = (int*)(part + 4 * NELEM);             // 320
    int*   k_idx     = max_s + NGROUP;                       // 4800
    int*   counter   = k_idx + NELEM;                        // 1

    k_pass1<<<NGROUP + NELEM, 256, 0, stream>>>(out_f, rowmean, proto_all, pn2_all, counter);
    k_select<<<BB, 64, 0, stream>>>(rowmean, max_s, k_idx);
    k_loss<<<NELEM, 64, 0, stream>>>(out_f, proto_all, pn2_all, max_s, k_idx,
                                     labels_query, att_loss, part, counter, out);
}

// Round 4
// 67.369 us; speedup vs baseline: 3.1543x; 3.1543x over previous
//
#include <hip/hip_runtime.h>

// Problem constants (match reference)
#define BB 64
#define N_WAY 5
#define N_SHOT 5
#define QUERY 15
#define NUM_SLOT 8
#define DD 640
#define IMGS (N_WAY * QUERY)      // 75
#define NS (BB * N_WAY * N_SHOT)  // 1600 support rows
#define NROWS 6400                // total rows
#define ROWSZ (NUM_SLOT * DD)     // 5120 floats per row
#define F4_PER_SLOT 160           // 640/4
#define NELEM (BB * IMGS)         // 4800 loss elements
#define NGROUP (BB * N_WAY)       // 320 support groups

// ---------------- K1: single streaming pass over out_f ----------------
// rowmean[6400][8] (per-row slot means), proto_all[320][8][640] (shot-means,
// all slots), pn2_all[320][8] (||proto||^2, all slots).
__global__ __launch_bounds__(256) void k_pass1(const float* __restrict__ out_f,
                                               float* __restrict__ rowmean,
                                               float* __restrict__ proto_all,
                                               float* __restrict__ pn2_all) {
    int b = blockIdx.x;
    int t = threadIdx.x;
    int slot = t >> 5;            // 0..7
    int l = t & 31;
    if (b < NGROUP) {
        const int g = b;          // support group j*5+c
        float4 acc[5];
        #pragma unroll
        for (int k = 0; k < 5; ++k) acc[k] = make_float4(0.f, 0.f, 0.f, 0.f);
        #pragma unroll
        for (int sh = 0; sh < N_SHOT; ++sh) {
            const float4* p = (const float4*)(out_f +
                ((size_t)((g * N_SHOT + sh) * NUM_SLOT + slot)) * DD);
            float s = 0.f;
            #pragma unroll
            for (int k = 0; k < 5; ++k) {
                float4 v = p[l + k * 32];
                acc[k].x += v.x; acc[k].y += v.y; acc[k].z += v.z; acc[k].w += v.w;
                s += (v.x + v.y) + (v.z + v.w);
            }
            #pragma unroll
            for (int off = 16; off; off >>= 1) s += __shfl_down(s, off, 32);
            if (l == 0) rowmean[(g * N_SHOT + sh) * NUM_SLOT + slot] = s * (1.f / DD);
        }
        float4* pp = (float4*)(proto_all + ((size_t)(g * NUM_SLOT + slot)) * DD);
        float ssq = 0.f;
        #pragma unroll
        for (int k = 0; k < 5; ++k) {
            acc[k].x *= 0.2f; acc[k].y *= 0.2f; acc[k].z *= 0.2f; acc[k].w *= 0.2f;
            pp[l + k * 32] = acc[k];
            ssq += acc[k].x * acc[k].x + acc[k].y * acc[k].y
                 + acc[k].z * acc[k].z + acc[k].w * acc[k].w;
        }
        #pragma unroll
        for (int off = 16; off; off >>= 1) ssq += __shfl_down(ssq, off, 32);
        if (l == 0) pn2_all[g * NUM_SLOT + slot] = ssq;
    } else {
        int r = NS + (b - NGROUP);   // query row
        const float4* p = (const float4*)(out_f + (size_t)r * ROWSZ) + slot * F4_PER_SLOT;
        float s = 0.f;
        #pragma unroll
        for (int k = 0; k < 5; ++k) {
            float4 v = p[l + k * 32];
            s += (v.x + v.y) + (v.z + v.w);
        }
        #pragma unroll
        for (int off = 16; off; off >>= 1) s += __shfl_down(s, off, 32);
        if (l == 0) rowmean[r * NUM_SLOT + slot] = s * (1.f / DD);
    }
}

// ---------------- K2: cover-select + prefix argmax + proto compaction ----------
// One block (one wave) per batch.
__global__ __launch_bounds__(64) void k_select(const float* __restrict__ rowmean,
                                               const float* __restrict__ proto_all,
                                               const float* __restrict__ pn2_all,
                                               int* __restrict__ max_s,
                                               int* __restrict__ k_idx,
                                               float* __restrict__ proto_c,
                                               float* __restrict__ pn2_c) {
    int j = blockIdx.x;           // 0..63
    int t = threadIdx.x;          // 0..63
    __shared__ float supm[N_WAY * NUM_SLOT];
    __shared__ int msS[N_WAY];
    __shared__ float qb[IMGS * NUM_SLOT];     // 600

    const float* qbase = rowmean + (size_t)(NS + j * IMGS) * NUM_SLOT;
    for (int i = t; i < IMGS * NUM_SLOT; i += 64) qb[i] = qbase[i];
    if (t < N_WAY * NUM_SLOT) {
        int c = t >> 3, s = t & 7;
        const float* sb = rowmean + (size_t)j * (N_WAY * N_SHOT * NUM_SLOT)
                          + c * (N_SHOT * NUM_SLOT) + s;
        float a = sb[0] + sb[8] + sb[16] + sb[24] + sb[32];
        supm[t] = a * 0.2f;
    }
    __syncthreads();

    // greedy cover select (serial, tiny; first-occurrence argmax among untaken)
    if (t == 0) {
        unsigned taken = 0u;
        #pragma unroll
        for (int c = 0; c < N_WAY; ++c) {
            float best = -3.0e38f; int bi = 0;
            #pragma unroll
            for (int s = 0; s < NUM_SLOT; ++s) {
                float v = supm[c * NUM_SLOT + s];
                if (!((taken >> s) & 1u) && v > best) { best = v; bi = s; }
            }
            taken |= (1u << bi);
            msS[c] = bi;
            max_s[j * N_WAY + c] = bi;
        }
    }
    __syncthreads();
    int ms0 = msS[0], ms1 = msS[1], ms2 = msS[2], ms3 = msS[3], ms4 = msS[4];

    // compact selected protos: proto_c[j*5+c][:] = proto_all[(j*5+c)*8+ms[c]][:]
    {
        int msA[N_WAY] = {ms0, ms1, ms2, ms3, ms4};
        #pragma unroll
        for (int c = 0; c < N_WAY; ++c) {
            int g = j * N_WAY + c;
            const float4* src = (const float4*)(proto_all + ((size_t)(g * NUM_SLOT + msA[c])) * DD);
            float4* dst = (float4*)(proto_c + (size_t)g * DD);
            for (int i = t; i < F4_PER_SLOT; i += 64) dst[i] = src[i];
            if (t == c) pn2_c[g] = pn2_all[g * NUM_SLOT + msA[c]];
        }
    }

    // per-step local argmax for step s = t (flat index s*5+c, first occurrence)
    float bv; int bi;
    {
        const float* q = &qb[t * NUM_SLOT];
        bv = q[ms0]; bi = t * N_WAY;
        float v;
        v = q[ms1]; if (v > bv) { bv = v; bi = t * N_WAY + 1; }
        v = q[ms2]; if (v > bv) { bv = v; bi = t * N_WAY + 2; }
        v = q[ms3]; if (v > bv) { bv = v; bi = t * N_WAY + 3; }
        v = q[ms4]; if (v > bv) { bv = v; bi = t * N_WAY + 4; }
    }
    // inclusive prefix scan; take later only if strictly greater
    #pragma unroll
    for (int off = 1; off < 64; off <<= 1) {
        float ov = __shfl_up(bv, off, 64);
        int   oi = __shfl_up(bi, off, 64);
        if (t >= off && !(bv > ov)) { bv = ov; bi = oi; }
    }
    k_idx[j * IMGS + t] = bi;
    float tv = __shfl(bv, 63, 64);
    int   ti = __shfl(bi, 63, 64);
    float bv2 = -3.0e38f; int bi2 = 0;
    if (t < IMGS - 64) {
        int s = 64 + t;
        const float* q = &qb[s * NUM_SLOT];
        bv2 = q[ms0]; bi2 = s * N_WAY;
        float v;
        v = q[ms1]; if (v > bv2) { bv2 = v; bi2 = s * N_WAY + 1; }
        v = q[ms2]; if (v > bv2) { bv2 = v; bi2 = s * N_WAY + 2; }
        v = q[ms3]; if (v > bv2) { bv2 = v; bi2 = s * N_WAY + 3; }
        v = q[ms4]; if (v > bv2) { bv2 = v; bi2 = s * N_WAY + 4; }
    }
    #pragma unroll
    for (int off = 1; off < 16; off <<= 1) {
        float ov = __shfl_up(bv2, off, 64);
        int   oi = __shfl_up(bi2, off, 64);
        if (t >= off && t < IMGS - 64 && !(bv2 > ov)) { bv2 = ov; bi2 = oi; }
    }
    if (t < IMGS - 64) {
        if (!(bv2 > tv)) { bv2 = tv; bi2 = ti; }
        k_idx[j * IMGS + 64 + t] = bi2;
    }
}

// ---------------- K3: scores + log-softmax + per-element loss/acc ----------------
// score_n = 2 q.p_n - ||p_n||^2  (||q||^2 cancels in log_softmax/argmax)
__global__ __launch_bounds__(64) void k_loss(const float* __restrict__ out_f,
                                             const float* __restrict__ proto_c,
                                             const float* __restrict__ pn2_c,
                                             const int* __restrict__ max_s,
                                             const int* __restrict__ k_idx,
                                             const int* __restrict__ labels_query,
                                             float* __restrict__ part) {
    int bid = blockIdx.x;             // j*75 + m
    int j = bid / IMGS, m = bid % IMGS;
    int t = threadIdx.x;              // 64

    int ms1 = max_s[j * N_WAY + m / QUERY];
    const float4* q1 = (const float4*)(out_f + (size_t)(NS + bid) * ROWSZ + ms1 * DD);

    int kk = k_idx[bid];
    int s2 = kk / N_WAY, c2 = kk % N_WAY;
    int ms2 = max_s[j * N_WAY + c2];
    const float4* q2 = (const float4*)(out_f +
        (size_t)(NS + j * IMGS + s2) * ROWSZ + ms2 * DD);

    const float4* pr = (const float4*)(proto_c + (size_t)j * N_WAY * DD);

    float s1[N_WAY] = {0, 0, 0, 0, 0};
    float s2a[N_WAY] = {0, 0, 0, 0, 0};
    for (int i = t; i < F4_PER_SLOT; i += 64) {
        float4 a = q1[i];
        float4 bq = q2[i];
        #pragma unroll
        for (int n = 0; n < N_WAY; ++n) {
            float4 p = pr[n * F4_PER_SLOT + i];
            s1[n]  += a.x * p.x + a.y * p.y + a.z * p.z + a.w * p.w;
            s2a[n] += bq.x * p.x + bq.y * p.y + bq.z * p.z + bq.w * p.w;
        }
    }
    #pragma unroll
    for (int n = 0; n < N_WAY; ++n) {
        #pragma unroll
        for (int off = 32; off; off >>= 1) {
            s1[n]  += __shfl_down(s1[n],  off, 64);
            s2a[n] += __shfl_down(s2a[n], off, 64);
        }
    }
    if (t == 0) {
        int label = labels_query[bid];
        const float* p2 = pn2_c + j * N_WAY;
        // path 1
        {
            float li[N_WAY]; float mx = -3.0e38f;
            #pragma unroll
            for (int n = 0; n < N_WAY; ++n) { li[n] = 2.f * s1[n] - p2[n]; mx = fmaxf(mx, li[n]); }
            float se = 0.f;
            #pragma unroll
            for (int n = 0; n < N_WAY; ++n) se += expf(li[n] - mx);
            float lse = mx + logf(se);
            int bi = 0; float bvv = li[0];
            #pragma unroll
            for (int n = 1; n < N_WAY; ++n) if (li[n] > bvv) { bvv = li[n]; bi = n; }
            part[0 * NELEM + bid] = -(li[label] - lse);
            part[2 * NELEM + bid] = (bi == label) ? 1.f : 0.f;
        }
        // path 2
        {
            float li[N_WAY]; float mx = -3.0e38f;
            #pragma unroll
            for (int n = 0; n < N_WAY; ++n) { li[n] = 2.f * s2a[n] - p2[n]; mx = fmaxf(mx, li[n]); }
            float se = 0.f;
            #pragma unroll
            for (int n = 0; n < N_WAY; ++n) se += expf(li[n] - mx);
            float lse = mx + logf(se);
            int bi = 0; float bvv = li[0];
            #pragma unroll
            for (int n = 1; n < N_WAY; ++n) if (li[n] > bvv) { bvv = li[n]; bi = n; }
            part[1 * NELEM + bid] = -(li[label] - lse);
            part[3 * NELEM + bid] = (bi == label) ? 1.f : 0.f;
        }
    }
}

// ---------------- K4: final deterministic tree reduction ----------------
__global__ void k_final(const float* __restrict__ part,
                        const float* __restrict__ att_loss,
                        float* __restrict__ out) {
    __shared__ float red[256];
    int t = threadIdx.x;              // 256
    for (int c = 0; c < 4; ++c) {
        float s = 0.f;
        for (int i = t; i < NELEM; i += 256) s += part[c * NELEM + i];
        red[t] = s;
        __syncthreads();
        for (int w = 128; w; w >>= 1) {
            if (t < w) red[t] += red[t + w];
            __syncthreads();
        }
        if (t == 0) {
            float v = red[0] / (float)NELEM;
            if (c == 0) v += 0.1f * att_loss[0];
            out[c] = v;
        }
        __syncthreads();
    }
}

extern "C" void kernel_launch(void* const* d_in, const int* in_sizes, int n_in,
                              void* d_out, int out_size, void* d_ws, size_t ws_size,
                              hipStream_t stream) {
    const float* out_f        = (const float*)d_in[0];
    // d_in[1] = labels_support (unused by the reference's train path)
    const int*   labels_query = (const int*)d_in[2];
    const float* att_loss     = (const float*)d_in[3];
    float* out = (float*)d_out;

    // workspace layout
    float* rowmean   = (float*)d_ws;                         // 51200 f
    float* proto_all = rowmean + NROWS * NUM_SLOT;           // 320*8*640
    float* pn2_all   = proto_all + NGROUP * NUM_SLOT * DD;   // 2560 f
    float* proto_c   = pn2_all + NGROUP * NUM_SLOT;          // 320*640
    float* pn2_c     = proto_c + NGROUP * DD;                // 320 f
    float* part      = pn2_c + NGROUP;                       // 4*4800 f
    int*   max_s     = (int*)(part + 4 * NELEM);             // 320 i
    int*   k_idx     = max_s + NGROUP;                       // 4800 i

    k_pass1<<<NGROUP + NELEM, 256, 0, stream>>>(out_f, rowmean, proto_all, pn2_all);
    k_select<<<BB, 64, 0, stream>>>(rowmean, proto_all, pn2_all, max_s, k_idx, proto_c, pn2_c);
    k_loss<<<NELEM, 64, 0, stream>>>(out_f, proto_c, pn2_c, max_s, k_idx, labels_query, part);
    k_final<<<1, 256, 0, stream>>>(part, att_loss, out);
}

// Round 5
// 47.383 us; speedup vs baseline: 4.4848x; 1.4218x over previous
//
#include <hip/hip_runtime.h>

// Problem constants (match reference)
#define BB 64
#define N_WAY 5
#define N_SHOT 5
#define QUERY 15
#define NUM_SLOT 8
#define DD 640
#define IMGS (N_WAY * QUERY)      // 75
#define NS (BB * N_WAY * N_SHOT)  // 1600 support rows
#define NROWS 6400                // total rows
#define ROWSZ (NUM_SLOT * DD)     // 5120 floats per row
#define F4_PER_SLOT 160           // 640/4
#define NELEM (BB * IMGS)         // 4800 loss elements
#define NGROUP (BB * N_WAY)       // 320 support groups
#define BPB 4                     // blocks per batch in k_batch
#define EPB 19                    // ceil(75/4) elements per block piece
#define NBATCHBLK (BB * BPB)      // 256

// ---------------- K1: single streaming pass over out_f ----------------
// rowmean[6400][8] (per-row slot means), proto_all[320][8][640] (shot-means,
// all slots), pn2_all[320][8] (||proto||^2, all slots).
__global__ __launch_bounds__(256) void k_pass1(const float* __restrict__ out_f,
                                               float* __restrict__ rowmean,
                                               float* __restrict__ proto_all,
                                               float* __restrict__ pn2_all) {
    int b = blockIdx.x;
    int t = threadIdx.x;
    int slot = t >> 5;            // 0..7
    int l = t & 31;
    if (b < NGROUP) {
        const int g = b;          // support group j*5+c
        float4 acc[5];
        #pragma unroll
        for (int k = 0; k < 5; ++k) acc[k] = make_float4(0.f, 0.f, 0.f, 0.f);
        #pragma unroll
        for (int sh = 0; sh < N_SHOT; ++sh) {
            const float4* p = (const float4*)(out_f +
                ((size_t)((g * N_SHOT + sh) * NUM_SLOT + slot)) * DD);
            float s = 0.f;
            #pragma unroll
            for (int k = 0; k < 5; ++k) {
                float4 v = p[l + k * 32];
                acc[k].x += v.x; acc[k].y += v.y; acc[k].z += v.z; acc[k].w += v.w;
                s += (v.x + v.y) + (v.z + v.w);
            }
            #pragma unroll
            for (int off = 16; off; off >>= 1) s += __shfl_down(s, off, 32);
            if (l == 0) rowmean[(g * N_SHOT + sh) * NUM_SLOT + slot] = s * (1.f / DD);
        }
        float4* pp = (float4*)(proto_all + ((size_t)(g * NUM_SLOT + slot)) * DD);
        float ssq = 0.f;
        #pragma unroll
        for (int k = 0; k < 5; ++k) {
            acc[k].x *= 0.2f; acc[k].y *= 0.2f; acc[k].z *= 0.2f; acc[k].w *= 0.2f;
            pp[l + k * 32] = acc[k];
            ssq += acc[k].x * acc[k].x + acc[k].y * acc[k].y
                 + acc[k].z * acc[k].z + acc[k].w * acc[k].w;
        }
        #pragma unroll
        for (int off = 16; off; off >>= 1) ssq += __shfl_down(ssq, off, 32);
        if (l == 0) pn2_all[g * NUM_SLOT + slot] = ssq;
    } else {
        int r = NS + (b - NGROUP);   // query row
        const float4* p = (const float4*)(out_f + (size_t)r * ROWSZ) + slot * F4_PER_SLOT;
        float s = 0.f;
        #pragma unroll
        for (int k = 0; k < 5; ++k) {
            float4 v = p[l + k * 32];
            s += (v.x + v.y) + (v.z + v.w);
        }
        #pragma unroll
        for (int off = 16; off; off >>= 1) s += __shfl_down(s, off, 32);
        if (l == 0) rowmean[r * NUM_SLOT + slot] = s * (1.f / DD);
    }
}

// ---------------- K2: per-batch fused select + prefix-argmax + loss ----------------
// 4 blocks per batch; each block redundantly computes the (cheap) selection and
// prefix scan from L2-resident rowmeans, then computes its slice of elements.
// part[c*256 + blk] = partial sums (nll1, nll2, acc1, acc2).
__global__ __launch_bounds__(256) void k_batch(const float* __restrict__ out_f,
                                               const float* __restrict__ rowmean,
                                               const float* __restrict__ proto_all,
                                               const float* __restrict__ pn2_all,
                                               const int* __restrict__ labels_query,
                                               float* __restrict__ part) {
    int blk = blockIdx.x;         // 0..255
    int j = blk >> 2;             // batch
    int piece = blk & 3;
    int t = threadIdx.x;          // 0..255
    int wave = t >> 6, lane = t & 63;

    __shared__ float qb[IMGS * NUM_SLOT];   // 600
    __shared__ float supm[N_WAY * NUM_SLOT];
    __shared__ int   msS[N_WAY];
    __shared__ float protoS[N_WAY * DD];    // 12.8 KB
    __shared__ float pn2S[N_WAY];
    __shared__ int   kS[IMGS];
    __shared__ float partial[4][4];         // [wave][channel]

    // stage query row-means + support slot means
    const float* qbase = rowmean + (size_t)(NS + j * IMGS) * NUM_SLOT;
    for (int i = t; i < IMGS * NUM_SLOT; i += 256) qb[i] = qbase[i];
    if (t < N_WAY * NUM_SLOT) {
        int c = t >> 3, s = t & 7;
        const float* sb = rowmean + (size_t)j * (N_WAY * N_SHOT * NUM_SLOT)
                          + c * (N_SHOT * NUM_SLOT) + s;
        supm[t] = (sb[0] + sb[8] + sb[16] + sb[24] + sb[32]) * 0.2f;
    }
    __syncthreads();

    // greedy cover select (serial, tiny; first-occurrence among untaken)
    if (t == 0) {
        unsigned taken = 0u;
        #pragma unroll
        for (int c = 0; c < N_WAY; ++c) {
            float best = -3.0e38f; int bi = 0;
            #pragma unroll
            for (int s = 0; s < NUM_SLOT; ++s) {
                float v = supm[c * NUM_SLOT + s];
                if (!((taken >> s) & 1u) && v > best) { best = v; bi = s; }
            }
            taken |= (1u << bi);
            msS[c] = bi;
        }
    }
    __syncthreads();

    if (wave == 0) {
        // wave 0: inclusive prefix argmax over flat (s, c), first-occurrence
        int ms0 = msS[0], ms1 = msS[1], ms2 = msS[2], ms3 = msS[3], ms4 = msS[4];
        float bv; int bi;
        {
            const float* q = &qb[lane * NUM_SLOT];
            bv = q[ms0]; bi = lane * N_WAY;
            float v;
            v = q[ms1]; if (v > bv) { bv = v; bi = lane * N_WAY + 1; }
            v = q[ms2]; if (v > bv) { bv = v; bi = lane * N_WAY + 2; }
            v = q[ms3]; if (v > bv) { bv = v; bi = lane * N_WAY + 3; }
            v = q[ms4]; if (v > bv) { bv = v; bi = lane * N_WAY + 4; }
        }
        #pragma unroll
        for (int off = 1; off < 64; off <<= 1) {
            float ov = __shfl_up(bv, off, 64);
            int   oi = __shfl_up(bi, off, 64);
            if (lane >= off && !(bv > ov)) { bv = ov; bi = oi; }
        }
        kS[lane] = bi;
        float tv = __shfl(bv, 63, 64);
        int   ti = __shfl(bi, 63, 64);
        float bv2 = -3.0e38f; int bi2 = 0;
        if (lane < IMGS - 64) {
            int s = 64 + lane;
            const float* q = &qb[s * NUM_SLOT];
            bv2 = q[ms0]; bi2 = s * N_WAY;
            float v;
            v = q[ms1]; if (v > bv2) { bv2 = v; bi2 = s * N_WAY + 1; }
            v = q[ms2]; if (v > bv2) { bv2 = v; bi2 = s * N_WAY + 2; }
            v = q[ms3]; if (v > bv2) { bv2 = v; bi2 = s * N_WAY + 3; }
            v = q[ms4]; if (v > bv2) { bv2 = v; bi2 = s * N_WAY + 4; }
        }
        #pragma unroll
        for (int off = 1; off < 16; off <<= 1) {
            float ov = __shfl_up(bv2, off, 64);
            int   oi = __shfl_up(bi2, off, 64);
            if (lane >= off && lane < IMGS - 64 && !(bv2 > ov)) { bv2 = ov; bi2 = oi; }
        }
        if (lane < IMGS - 64) {
            if (!(bv2 > tv)) { bv2 = tv; bi2 = ti; }
            kS[64 + lane] = bi2;
        }
    } else {
        // waves 1-3 (192 threads): stage the 5 selected protos (+ pn2) into LDS
        int idx = t - 64;
        for (int i = idx; i < N_WAY * F4_PER_SLOT; i += 192) {
            int c = i / F4_PER_SLOT, r = i - c * F4_PER_SLOT;
            int g = j * N_WAY + c;
            ((float4*)protoS)[i] =
                ((const float4*)(proto_all + ((size_t)(g * NUM_SLOT + msS[c])) * DD))[r];
        }
        if (idx < N_WAY) pn2S[idx] = pn2_all[(j * N_WAY + idx) * NUM_SLOT + msS[idx]];
    }
    __syncthreads();

    // loss phase: elements [piece*EPB, min(75,(piece+1)*EPB)), strided by wave
    int e_lo = piece * EPB;
    int e_hi = (piece + 1) * EPB; if (e_hi > IMGS) e_hi = IMGS;
    float lnll1 = 0.f, lnll2 = 0.f, lacc1 = 0.f, lacc2 = 0.f;   // lane 0 only
    for (int m = e_lo + wave; m < e_hi; m += 4) {
        int bid = j * IMGS + m;
        int ms1 = msS[m / QUERY];
        const float4* q1 = (const float4*)(out_f + (size_t)(NS + bid) * ROWSZ + ms1 * DD);
        int kk = kS[m];
        int s2 = kk / N_WAY, c2 = kk - s2 * N_WAY;
        int ms2 = msS[c2];
        const float4* q2 = (const float4*)(out_f +
            (size_t)(NS + j * IMGS + s2) * ROWSZ + ms2 * DD);

        float s1[N_WAY] = {0, 0, 0, 0, 0};
        float s2a[N_WAY] = {0, 0, 0, 0, 0};
        for (int i = lane; i < F4_PER_SLOT; i += 64) {
            float4 a = q1[i];
            float4 bq = q2[i];
            #pragma unroll
            for (int n = 0; n < N_WAY; ++n) {
                float4 p = ((const float4*)protoS)[n * F4_PER_SLOT + i];
                s1[n]  += a.x * p.x + a.y * p.y + a.z * p.z + a.w * p.w;
                s2a[n] += bq.x * p.x + bq.y * p.y + bq.z * p.z + bq.w * p.w;
            }
        }
        #pragma unroll
        for (int n = 0; n < N_WAY; ++n) {
            #pragma unroll
            for (int off = 32; off; off >>= 1) {
                s1[n]  += __shfl_down(s1[n],  off, 64);
                s2a[n] += __shfl_down(s2a[n], off, 64);
            }
        }
        if (lane == 0) {
            int label = labels_query[bid];
            // path 1: score_n = 2 q.p_n - ||p_n||^2 (||q||^2 cancels)
            {
                float li[N_WAY]; float mx = -3.0e38f;
                #pragma unroll
                for (int n = 0; n < N_WAY; ++n) { li[n] = 2.f * s1[n] - pn2S[n]; mx = fmaxf(mx, li[n]); }
                float se = 0.f;
                #pragma unroll
                for (int n = 0; n < N_WAY; ++n) se += expf(li[n] - mx);
                float lse = mx + logf(se);
                int bi = 0; float bvv = li[0];
                #pragma unroll
                for (int n = 1; n < N_WAY; ++n) if (li[n] > bvv) { bvv = li[n]; bi = n; }
                lnll1 += -(li[label] - lse);
                lacc1 += (bi == label) ? 1.f : 0.f;
            }
            // path 2
            {
                float li[N_WAY]; float mx = -3.0e38f;
                #pragma unroll
                for (int n = 0; n < N_WAY; ++n) { li[n] = 2.f * s2a[n] - pn2S[n]; mx = fmaxf(mx, li[n]); }
                float se = 0.f;
                #pragma unroll
                for (int n = 0; n < N_WAY; ++n) se += expf(li[n] - mx);
                float lse = mx + logf(se);
                int bi = 0; float bvv = li[0];
                #pragma unroll
                for (int n = 1; n < N_WAY; ++n) if (li[n] > bvv) { bvv = li[n]; bi = n; }
                lnll2 += -(li[label] - lse);
                lacc2 += (bi == label) ? 1.f : 0.f;
            }
        }
    }
    if (lane == 0) {
        partial[wave][0] = lnll1;
        partial[wave][1] = lnll2;
        partial[wave][2] = lacc1;
        partial[wave][3] = lacc2;
    }
    __syncthreads();
    if (t == 0) {
        #pragma unroll
        for (int c = 0; c < 4; ++c)
            part[c * NBATCHBLK + blk] =
                partial[0][c] + partial[1][c] + partial[2][c] + partial[3][c];
    }
}

// ---------------- K3: final deterministic tree reduction (256 partials) --------
__global__ __launch_bounds__(256) void k_final(const float* __restrict__ part,
                                               const float* __restrict__ att_loss,
                                               float* __restrict__ out) {
    __shared__ float red[256];
    int t = threadIdx.x;              // 256
    for (int c = 0; c < 4; ++c) {
        red[t] = part[c * NBATCHBLK + t];
        __syncthreads();
        for (int w = 128; w; w >>= 1) {
            if (t < w) red[t] += red[t + w];
            __syncthreads();
        }
        if (t == 0) {
            float v = red[0] / (float)NELEM;
            if (c == 0) v += 0.1f * att_loss[0];
            out[c] = v;
        }
        __syncthreads();
    }
}

extern "C" void kernel_launch(void* const* d_in, const int* in_sizes, int n_in,
                              void* d_out, int out_size, void* d_ws, size_t ws_size,
                              hipStream_t stream) {
    const float* out_f        = (const float*)d_in[0];
    // d_in[1] = labels_support (unused by the reference's train path)
    const int*   labels_query = (const int*)d_in[2];
    const float* att_loss     = (const float*)d_in[3];
    float* out = (float*)d_out;

    // workspace layout
    float* rowmean   = (float*)d_ws;                         // 51200 f
    float* proto_all = rowmean + NROWS * NUM_SLOT;           // 320*8*640 f
    float* pn2_all   = proto_all + NGROUP * NUM_SLOT * DD;   // 2560 f
    float* part      = pn2_all + NGROUP * NUM_SLOT;          // 4*256 f

    k_pass1<<<NGROUP + NELEM, 256, 0, stream>>>(out_f, rowmean, proto_all, pn2_all);
    k_batch<<<NBATCHBLK, 256, 0, stream>>>(out_f, rowmean, proto_all, pn2_all,
                                           labels_query, part);
    k_final<<<1, 256, 0, stream>>>(part, att_loss, out);
}